// Round 15
// baseline (2500.776 us; speedup 1.0000x reference)
//
#include <hip/hip_runtime.h>

#define NPTS   4096
#define NBATCH 4
#define KNN    16
#define DMODEL 512
#define DPOINT 128
#define QKVLD  1536              // row stride of fused q|k|v buffer

#define BN 128
#define BK 64

typedef unsigned short bfu;                                     // bf16 bits
typedef __attribute__((ext_vector_type(8))) short short8;       // MFMA A/B frag
typedef __attribute__((ext_vector_type(4))) float f32x4;        // MFMA C/D frag

__device__ __forceinline__ bfu f2bf(float f) {                  // RNE f32->bf16
    unsigned u = __builtin_bit_cast(unsigned, f);
    return (bfu)((u + 0x7fffu + ((u >> 16) & 1u)) >> 16);
}
__device__ __forceinline__ float bf2f(bfu h) {
    unsigned u = ((unsigned)h) << 16;
    return __builtin_bit_cast(float, u);
}

__device__ __forceinline__ void gload_lds16(const bfu* g, bfu* l) {
    __builtin_amdgcn_global_load_lds(
        (const __attribute__((address_space(1))) void*)g,
        (__attribute__((address_space(3))) void*)l, 16, 0, 0);
}

// ---------------------------------------------------------------------------
// KNN v9: r4's exact branchy gated scan (fastest measured: 718us) +
// r8's two-pass 32KB LDS staging (correctness-proven) + launch_bounds(256,3).
// Occupancy = floor(512/VGPR) waves/SIMD: the untried 3-wave plateau needs
// VGPR in [129,170] — the ~160-reg working set FITS (unlike the failed 4+
// wave caps at <=128 which spilled, r6/r8). LDS 32KB -> 3 blocks/CU.
// Scan order per thread is increasing m across both halves -> same
// insertion-sort result; merge + writeout unchanged from r4.
// Branchless insert (r13) measured SLOWER (2x VALU work) — keep the gate.
// ---------------------------------------------------------------------------
#define TPQ  8                   // threads per query
#define QPB  32                  // queries per block (QPB*TPQ = 256)
#define HALF 2048                // points staged per pass (32 KB)

__device__ __forceinline__ void knn_merge_level(float* bd, int* bi, int lvl)
{
    float pd[KNN]; int pi[KNN];
#pragma unroll
    for (int i = 0; i < KNN; ++i) {              // partner's list, reversed
        pd[i] = __shfl_xor(bd[KNN-1-i], lvl);
        pi[i] = __shfl_xor(bi[KNN-1-i], lvl);
    }
#pragma unroll
    for (int i = 0; i < KNN; ++i) {              // lex-min -> lowest 16, bitonic
        bool take = (pd[i] < bd[i]) || (pd[i] == bd[i] && pi[i] < bi[i]);
        if (take) { bd[i] = pd[i]; bi[i] = pi[i]; }
    }
#pragma unroll
    for (int s = 8; s >= 1; s >>= 1) {           // bitonic merge network
#pragma unroll
        for (int i = 0; i < KNN; ++i) {
            if ((i & s) == 0) {
                const int j = i + s;
                bool sw = (bd[j] < bd[i]) || (bd[j] == bd[i] && bi[j] < bi[i]);
                if (sw) {
                    float td = bd[i]; bd[i] = bd[j]; bd[j] = td;
                    int   ti = bi[i]; bi[i] = bi[j]; bi[j] = ti;
                }
            }
        }
    }
}

__global__ __launch_bounds__(256, 3) void knn_kernel(const float* __restrict__ xyz,
                                                     int* __restrict__ knn_out)
{
    __shared__ float4 pts[HALF];   // 32 KB
    const int b    = blockIdx.y;
    const int tid  = threadIdx.x;
    const int qloc = tid >> 3;            // 0..31
    const int sub  = tid & 7;             // 0..7
    const int n    = blockIdx.x * QPB + qloc;

    const float* bx = xyz + (size_t)b * NPTS * 3;
    const float mex = bx[n*3+0], mey = bx[n*3+1], mez = bx[n*3+2];
    const float mew = mex*mex + mey*mey + mez*mez;

    float bd[KNN];
    int   bi[KNN];
#pragma unroll
    for (int i = 0; i < KNN; ++i) { bd[i] = 3.4e38f; bi[i] = -1; }

    for (int h = 0; h < NPTS / HALF; ++h) {
        __syncthreads();                  // previous pass fully scanned
        for (int i = tid; i < HALF; i += 256) {
            const int g = h * HALF + i;
            float x = bx[g*3+0], y = bx[g*3+1], z = bx[g*3+2];
            pts[i] = make_float4(x, y, z, x*x + y*y + z*z);
        }
        __syncthreads();

        // interleaved slice within the half: m_local = sub + 8*t (gated scan)
        for (int t0 = 0; t0 < HALF / TPQ; t0 += 8) {
            float d[8];
#pragma unroll
            for (int j = 0; j < 8; ++j) {
                float4 o = pts[sub + ((t0 + j) << 3)];
                d[j] = mew + o.w - 2.f*(mex*o.x + mey*o.y + mez*o.z);
            }
            float mn = fminf(fminf(fminf(d[0],d[1]),fminf(d[2],d[3])),
                             fminf(fminf(d[4],d[5]),fminf(d[6],d[7])));
            if (mn < bd[KNN-1]) {
#pragma unroll
                for (int j = 0; j < 8; ++j) {
                    float dj = d[j];
                    if (dj < bd[KNN-1]) {
                        const int m = h * HALF + sub + ((t0 + j) << 3);
#pragma unroll
                        for (int i = KNN-1; i >= 1; --i) {
                            float dp = bd[i-1];
                            if (dp > dj)        { bd[i] = dp; bi[i] = bi[i-1]; }
                            else if (bd[i] > dj){ bd[i] = dj; bi[i] = m; }
                        }
                        if (bd[0] > dj) { bd[0] = dj; bi[0] = m; }
                    }
                }
            }
        }
    }

    // merge the 8 per-slice sorted lists (lanes sub^1, sub^2, sub^4)
    knn_merge_level(bd, bi, 1);
    knn_merge_level(bd, bi, 2);
    knn_merge_level(bd, bi, 4);

    // all 8 threads now hold the final sorted list; each writes 2 entries
    int* orow = knn_out + ((size_t)b*NPTS + n) * KNN;
    const int base = b * NPTS;
    orow[sub*2+0] = base + bi[sub*2+0];
    orow[sub*2+1] = base + bi[sub*2+1];
}

// ---------------------------------------------------------------------------
// One-shot weight prep: transpose-convert all 8 weight matrices (one launch).
// ---------------------------------------------------------------------------
__global__ __launch_bounds__(256) void prep_weights(
    const float* __restrict__ fc1_w, const float* __restrict__ wq,
    const float* __restrict__ wk,    const float* __restrict__ wv,
    const float* __restrict__ d2_w,  const float* __restrict__ g1_w,
    const float* __restrict__ g2_w,  const float* __restrict__ fc2_w,
    bfu* __restrict__ fc1T, bfu* __restrict__ qkvT, bfu* __restrict__ d2T,
    bfu* __restrict__ g1T,  bfu* __restrict__ g2T,  bfu* __restrict__ fc2T)
{
    int i = blockIdx.x * 256 + threadIdx.x;
    const int S1 = DPOINT * DMODEL;      // 65536
    const int S2 = DMODEL * DMODEL;      // 262144
    if (i < S1) { fc1T[i] = f2bf(fc1_w[(size_t)(i & 127) * DMODEL + (i >> 7)]); return; }
    i -= S1;
    if (i < S2) { qkvT[i]        = f2bf(wq[(size_t)(i & 511) * DMODEL + (i >> 9)]); return; }
    i -= S2;
    if (i < S2) { qkvT[S2 + i]   = f2bf(wk[(size_t)(i & 511) * DMODEL + (i >> 9)]); return; }
    i -= S2;
    if (i < S2) { qkvT[2*S2 + i] = f2bf(wv[(size_t)(i & 511) * DMODEL + (i >> 9)]); return; }
    i -= S2;
    if (i < S2) { d2T[i] = f2bf(d2_w[(size_t)(i & 511) * DMODEL + (i >> 9)]); return; }
    i -= S2;
    if (i < S2) { g1T[i] = f2bf(g1_w[(size_t)(i & 511) * DMODEL + (i >> 9)]); return; }
    i -= S2;
    if (i < S2) { g2T[i] = f2bf(g2_w[(size_t)(i & 511) * DMODEL + (i >> 9)]); return; }
    i -= S2;
    if (i < S1) { fc2T[i] = f2bf(fc2_w[(size_t)(i & 511) * DPOINT + (i >> 9)]); return; }
}

__global__ __launch_bounds__(256) void cvt_bf16(const float* __restrict__ src,
                                                bfu* __restrict__ dst, int n4)
{
    int i = blockIdx.x * 256 + threadIdx.x;
    if (i < n4) {
        float4 v = ((const float4*)src)[i];
        bfu* d = dst + (size_t)i * 4;
        d[0] = f2bf(v.x); d[1] = f2bf(v.y); d[2] = f2bf(v.z); d[3] = f2bf(v.w);
    }
}

// ---------------------------------------------------------------------------
// pos_h = relu(rel @ d1_w + d1_b), materialized per chunk (memory-bound).
// ---------------------------------------------------------------------------
__global__ __launch_bounds__(256) void pos_h_kernel(
    const float* __restrict__ xyz, const int* __restrict__ knng,
    const float* __restrict__ d1w, const float* __restrict__ d1b,
    bfu* __restrict__ out, int row_base)
{
    const int idx  = blockIdx.x * 256 + threadIdx.x;
    const int rloc = idx >> 6;                // chunk-local row
    const int c0   = (idx & 63) * 8;
    const int grow = row_base + rloc;
    const int p    = grow >> 4;
    const int nb   = knng[grow];
    const float rx = xyz[(size_t)p*3+0] - xyz[(size_t)nb*3+0];
    const float ry = xyz[(size_t)p*3+1] - xyz[(size_t)nb*3+1];
    const float rz = xyz[(size_t)p*3+2] - xyz[(size_t)nb*3+2];
    short8 ov;
#pragma unroll
    for (int j = 0; j < 8; ++j) {
        const int k = c0 + j;
        float v = d1b[k];
        v = fmaf(rx, d1w[k],        v);
        v = fmaf(ry, d1w[512 + k],  v);
        v = fmaf(rz, d1w[1024 + k], v);
        ov[j] = (short)f2bf(fmaxf(v, 0.f));
    }
    *(short8*)&out[(size_t)rloc * DMODEL + c0] = ov;
}

// ---------------------------------------------------------------------------
// MFMA GEMM, m97 structure, BMt x 128 tile, BK=64, 4 waves, 16x16x32 bf16,
// global_load_lds width 16, 2 barriers per K-step. Plain bf16 A (gload_lds).
// 1D grid + bijective XCD-chunk swizzle + bn-fastest (r10: -200us wall).
// AIN:  epilogue writes posc (Cout, bf16) AND ainb = q[p]-k[g]+pos (auxb).
// SMAX: fused scale+softmax(16 neighbor rows)+attn write(f32)+res reduce.
// ---------------------------------------------------------------------------
template<int BMt, bool BIAS, bool RELU, bool OUTBF, bool RESID, bool AIN, bool SMAX>
__global__ __launch_bounds__(256) void gemm_mfma(
    const bfu* __restrict__ A, const bfu* __restrict__ BT,
    const float* __restrict__ bias, const float* __restrict__ resid,
    void* __restrict__ Cout, int M, int Kd, int Nd,
    const int* __restrict__ knng,
    const bfu* __restrict__ qb, const bfu* __restrict__ kb,
    const bfu* __restrict__ posc, const bfu* __restrict__ vb,
    bfu* __restrict__ auxb, int row_base)
{
    constexpr int MF  = BMt / 32;     // m-fragments per wave (4 or 2)
    constexpr int RPW = BMt / 4;      // A rows staged per wave

    __shared__ bfu As[BMt * BK];
    __shared__ bfu Bs[BN * BK];

    const int tid  = threadIdx.x;
    const int lane = tid & 63;
    const int w    = tid >> 6;

    // XCD-chunk swizzle (bijective since gridDim.x % 8 == 0), bn fastest
    const int nbn     = Nd / BN;
    const int q8      = gridDim.x >> 3;
    const int logical = (blockIdx.x & 7) * q8 + (blockIdx.x >> 3);
    const int bm      = (logical / nbn) * BMt;
    const int bn      = (logical % nbn) * BN;

    const int wm   = (w >> 1) * (BMt / 2);
    const int wn   = (w & 1) * 64;
    const int lrow = lane & 15;
    const int kgrp = lane >> 4;

    f32x4 acc[MF][4];
#pragma unroll
    for (int m = 0; m < MF; ++m)
#pragma unroll
        for (int n = 0; n < 4; ++n) acc[m][n] = (f32x4){0.f, 0.f, 0.f, 0.f};

    for (int k0 = 0; k0 < Kd; k0 += BK) {
        __syncthreads();   // previous tile fully consumed

        // ---- stage B
        {
            int r0 = w * 32;
            const bfu* gB = BT + (size_t)(bn + r0 + (lane >> 3)) * Kd + k0 + (lane & 7) * 8;
            bfu* lB = Bs + r0 * BK;
#pragma unroll
            for (int i = 0; i < 4; ++i)
                gload_lds16(gB + (size_t)i * 8 * Kd, lB + i * 8 * BK);
        }
        // ---- stage A
        {
            int r0 = w * RPW;
            const bfu* gA = A + (size_t)(bm + r0 + (lane >> 3)) * Kd + k0 + (lane & 7) * 8;
            bfu* lA = As + r0 * BK;
#pragma unroll
            for (int i = 0; i < RPW / 8; ++i)
                gload_lds16(gA + (size_t)i * 8 * Kd, lA + i * 8 * BK);
        }

        __syncthreads();

        // ---- compute
#pragma unroll
        for (int kk = 0; kk < BK; kk += 32) {
            short8 af[MF], bfr[4];
#pragma unroll
            for (int m = 0; m < MF; ++m)
                af[m] = *(const short8*)&As[(wm + m * 16 + lrow) * BK + kk + kgrp * 8];
#pragma unroll
            for (int n = 0; n < 4; ++n)
                bfr[n] = *(const short8*)&Bs[(wn + n * 16 + lrow) * BK + kk + kgrp * 8];
#pragma unroll
            for (int m = 0; m < MF; ++m)
#pragma unroll
                for (int n = 0; n < 4; ++n)
                    acc[m][n] = __builtin_amdgcn_mfma_f32_16x16x32_bf16(
                        af[m], bfr[n], acc[m][n], 0, 0, 0);
        }
    }

    if constexpr (AIN) {
        // pos = acc + bias -> posc (bf16, Cout); ainb = q[p]-k[g]+pos (auxb)
#pragma unroll
        for (int m = 0; m < MF; ++m) {
            const int row0 = bm + wm + m * 16 + kgrp * 4;    // chunk-local
            int p4[4], g4[4];
#pragma unroll
            for (int r = 0; r < 4; ++r) {
                const int grow = row_base + row0 + r;
                p4[r] = grow >> 4;
                g4[r] = knng[grow];
            }
#pragma unroll
            for (int n = 0; n < 4; ++n) {
                const int col = bn + wn + n * 16 + lrow;
                const float bv = bias[col];
#pragma unroll
                for (int r = 0; r < 4; ++r) {
                    const size_t o = (size_t)(row0 + r) * DMODEL + col;
                    bfu pb = f2bf(acc[m][n][r] + bv);
                    ((bfu*)Cout)[o] = pb;
                    float qv = bf2f(qb[(size_t)p4[r] * QKVLD + col]);
                    float kv = bf2f(kb[(size_t)g4[r] * QKVLD + col]);
                    auxb[o] = f2bf(qv - kv + bf2f(pb));
                }
            }
        }
        return;
    }

    if constexpr (SMAX) {
        // logits -> softmax over the 16 neighbor rows of each point -> attn
        // (f32, to Cout) + res partial reduce (bf16, to auxb).
        const float scale = 0.044194173824159216f;   // 1/sqrt(512)
#pragma unroll
        for (int m = 0; m < MF; ++m) {
            const int row0 = bm + wm + m * 16 + kgrp * 4;    // chunk-local
            const int ploc = (bm + wm + m * 16) >> 4;        // chunk-local point
            int gnb4[4];
#pragma unroll
            for (int r = 0; r < 4; ++r) gnb4[r] = knng[(size_t)row_base + row0 + r];
#pragma unroll
            for (int n = 0; n < 4; ++n) {
                const int col = bn + wn + n * 16 + lrow;
                const float bv = bias[col];
                float v0 = (acc[m][n][0] + bv) * scale;
                float v1 = (acc[m][n][1] + bv) * scale;
                float v2 = (acc[m][n][2] + bv) * scale;
                float v3 = (acc[m][n][3] + bv) * scale;
                float mx = fmaxf(fmaxf(v0, v1), fmaxf(v2, v3));
                mx = fmaxf(mx, __shfl_xor(mx, 16));
                mx = fmaxf(mx, __shfl_xor(mx, 32));
                float e0 = __expf(v0 - mx), e1 = __expf(v1 - mx);
                float e2 = __expf(v2 - mx), e3 = __expf(v3 - mx);
                float s = e0 + e1 + e2 + e3;
                s += __shfl_xor(s, 16);
                s += __shfl_xor(s, 32);
                const float inv = 1.f / s;
                float a0 = e0*inv, a1 = e1*inv, a2 = e2*inv, a3 = e3*inv;
                float* ao = (float*)Cout;
                ao[(size_t)(row0 + 0) * DMODEL + col] = a0;
                ao[(size_t)(row0 + 1) * DMODEL + col] = a1;
                ao[(size_t)(row0 + 2) * DMODEL + col] = a2;
                ao[(size_t)(row0 + 3) * DMODEL + col] = a3;
                float res = 0.f;
                res = fmaf(a0, bf2f(vb[(size_t)gnb4[0]*QKVLD + col]) + bf2f(posc[(size_t)(row0+0)*DMODEL + col]), res);
                res = fmaf(a1, bf2f(vb[(size_t)gnb4[1]*QKVLD + col]) + bf2f(posc[(size_t)(row0+1)*DMODEL + col]), res);
                res = fmaf(a2, bf2f(vb[(size_t)gnb4[2]*QKVLD + col]) + bf2f(posc[(size_t)(row0+2)*DMODEL + col]), res);
                res = fmaf(a3, bf2f(vb[(size_t)gnb4[3]*QKVLD + col]) + bf2f(posc[(size_t)(row0+3)*DMODEL + col]), res);
                res += __shfl_xor(res, 16);
                res += __shfl_xor(res, 32);
                if (kgrp == 0) {
                    const size_t pglob = (size_t)(row_base >> 4) + ploc;
                    auxb[pglob * DMODEL + col] = f2bf(res);
                }
            }
        }
        return;
    }

    // ---- standard epilogue: C row = (lane>>4)*4 + reg, col = lane&15
#pragma unroll
    for (int m = 0; m < MF; ++m) {
#pragma unroll
        for (int n = 0; n < 4; ++n) {
            int col = bn + wn + n * 16 + lrow;
            float bv = BIAS ? bias[col] : 0.f;
#pragma unroll
            for (int r = 0; r < 4; ++r) {
                int row = bm + wm + m * 16 + kgrp * 4 + r;
                float v = acc[m][n][r] + bv;
                if (RESID) v += resid[(size_t)row * Nd + col];
                if (RELU)  v = fmaxf(v, 0.f);
                if (OUTBF) ((bfu*)Cout)[(size_t)row * Nd + col] = f2bf(v);
                else     ((float*)Cout)[(size_t)row * Nd + col] = v;
            }
        }
    }
}

// ---------------------------------------------------------------------------
extern "C" void kernel_launch(void* const* d_in, const int* in_sizes, int n_in,
                              void* d_out, int out_size, void* d_ws, size_t ws_size,
                              hipStream_t stream)
{
    const float* xyz      = (const float*)d_in[0];
    const float* features = (const float*)d_in[1];
    const float* fc1_w    = (const float*)d_in[2];
    const float* fc1_b    = (const float*)d_in[3];
    const float* fc2_w    = (const float*)d_in[4];
    const float* fc2_b    = (const float*)d_in[5];
    const float* wq       = (const float*)d_in[6];
    const float* wk       = (const float*)d_in[7];
    const float* wv       = (const float*)d_in[8];
    const float* d1_w     = (const float*)d_in[9];
    const float* d1_b     = (const float*)d_in[10];
    const float* d2_w     = (const float*)d_in[11];
    const float* d2_b     = (const float*)d_in[12];
    const float* g1_w     = (const float*)d_in[13];
    const float* g1_b     = (const float*)d_in[14];
    const float* g2_w     = (const float*)d_in[15];
    const float* g2_b     = (const float*)d_in[16];

    const size_t Mpts  = (size_t)NBATCH * NPTS;      // 16384
    const size_t Mrows = Mpts * KNN;                 // 262144
    float* out_res  = (float*)d_out;                 // [16384,128]
    float* out_attn = (float*)d_out + Mpts * DPOINT; // [16384,16,512] f32

    // ---- workspace layout (resb aliases xb: xb dead after qkv GEMM)
    size_t off = 0;
    auto ab = [&](size_t elems) { bfu* r = (bfu*)((char*)d_ws + off); off += elems * 2; return r; };
    bfu* fc1T  = ab((size_t)DMODEL * DPOINT);        // [512][128]
    bfu* qkvT  = ab((size_t)QKVLD * DMODEL);         // [1536][512] = wq^T|wk^T|wv^T
    bfu* d2T   = ab((size_t)DMODEL * DMODEL);
    bfu* g1T   = ab((size_t)DMODEL * DMODEL);
    bfu* g2T   = ab((size_t)DMODEL * DMODEL);
    bfu* fc2T  = ab((size_t)DPOINT * DMODEL);        // [128][512]
    bfu* featb = ab(Mpts * DPOINT);
    bfu* xb    = ab(Mpts * DMODEL);                  // reused as resb
    bfu* qkvb  = ab(Mpts * QKVLD);                   // [16384][1536] q|k|v
    bfu* resb  = xb;
    int* knng  = (int*)((char*)d_ws + off); off += Mrows * 4;

    // prefer nchunk=4: 3 x 64MB chunk buffers -> L3-resident, grid still full
    int nchunk = 32;
    {
        const int cands[4] = {4, 8, 16, 32};
        for (int i = 0; i < 4; ++i) {
            size_t need = off + 3ull * (Mrows / cands[i]) * DMODEL * 2;
            if (need <= ws_size) { nchunk = cands[i]; break; }
        }
    }
    const size_t Rc  = Mrows / nchunk;               // rows per chunk
    bfu* posc = ab(Rc * DMODEL);
    bfu* hc   = ab(Rc * DMODEL);
    bfu* ainb = ab(Rc * DMODEL);

    // ---- KNN + conversions
    knn_kernel<<<dim3(NPTS/QPB, NBATCH), 256, 0, stream>>>(xyz, knng);

    {
        const int total = 2 * DPOINT * DMODEL + 6 * DMODEL * DMODEL;
        prep_weights<<<dim3((total + 255) / 256), 256, 0, stream>>>(
            fc1_w, wq, wk, wv, d2_w, g1_w, g2_w, fc2_w,
            fc1T, qkvT, d2T, g1T, g2T, fc2T);
    }
    cvt_bf16<<<dim3((Mpts*DPOINT/4+255)/256), 256, 0, stream>>>(features, featb, (int)(Mpts*DPOINT/4));

#define GARGS(Ap, Bp, biasp, residp, Cp, M_, K_, N_, auxp, rb) \
    (Ap), (Bp), (biasp), (residp), (Cp), (int)(M_), (int)(K_), (int)(N_), \
    knng, qkvb, qkvb + DMODEL, posc, qkvb + 2*DMODEL, (auxp), (int)(rb)

    // ---- stage B: x = feat @ fc1 + b ; qkv = x @ [wq|wk|wv]  (one GEMM)
    gemm_mfma<128, true,  false, true,  false, false, false><<<dim3((Mpts/128)*(DMODEL/BN)), 256, 0, stream>>>(
        GARGS(featb, fc1T, fc1_b, nullptr, xb, Mpts, DPOINT, DMODEL, resb, 0));
    gemm_mfma<128, false, false, true,  false, false, false><<<dim3((Mpts/128)*(QKVLD/BN)), 256, 0, stream>>>(
        GARGS(xb, qkvT, nullptr, nullptr, qkvb, Mpts, DMODEL, QKVLD, resb, 0));

    // ---- chunked per-neighbor pipeline (all GEMMs plain, gload_lds-staged)
    for (int c = 0; c < nchunk; ++c) {
        const size_t rb = (size_t)c * Rc;
        float* attn_c = out_attn + rb * DMODEL;

        // pos_h = relu(rel@d1+b1) materialized into hc (memory-bound)
        pos_h_kernel<<<dim3((unsigned)(Rc/4)), 256, 0, stream>>>(xyz, knng, d1_w, d1_b, hc, (int)rb);

#define CHUNK_LAUNCH(BMT) \
        gemm_mfma<BMT, true, false, true, false, true, false><<<dim3((unsigned)((Rc/BMT)*(DMODEL/BN))), 256, 0, stream>>>( \
            GARGS(hc, d2T, d2_b, nullptr, posc, Rc, DMODEL, DMODEL, ainb, rb)); \
        gemm_mfma<BMT, true, true,  true, false, false, false><<<dim3((unsigned)((Rc/BMT)*(DMODEL/BN))), 256, 0, stream>>>( \
            GARGS(ainb, g1T, g1_b, nullptr, hc, Rc, DMODEL, DMODEL, resb, rb)); \
        gemm_mfma<BMT, false, false, false, false, false, true><<<dim3((unsigned)((Rc/BMT)*(DMODEL/BN))), 256, 0, stream>>>( \
            GARGS(hc, g2T, g2_b, nullptr, attn_c, Rc, DMODEL, DMODEL, resb, rb));

        if (Rc >= 32768) { CHUNK_LAUNCH(128) }
        else             { CHUNK_LAUNCH(64)  }
#undef CHUNK_LAUNCH
    }

    // ---- out = res @ fc2 + b + features
    gemm_mfma<128, true, false, false, true, false, false><<<dim3((Mpts/128)*(DPOINT/BN)), 256, 0, stream>>>(
        GARGS(resb, fc2T, fc2_b, features, out_res, Mpts, DMODEL, DPOINT, resb, 0));
#undef GARGS
}

// Round 16
// 1970.064 us; speedup vs baseline: 1.2694x; 1.2694x over previous
//
#include <hip/hip_runtime.h>

#define NPTS   4096
#define NBATCH 4
#define KNN    16
#define DMODEL 512
#define DPOINT 128
#define QKVLD  1536              // row stride of fused q|k|v buffer

#define BN 128
#define BK 64

typedef unsigned short bfu;                                     // bf16 bits
typedef __attribute__((ext_vector_type(8))) short short8;       // MFMA A/B frag
typedef __attribute__((ext_vector_type(4))) float f32x4;        // MFMA C/D frag

__device__ __forceinline__ bfu f2bf(float f) {                  // RNE f32->bf16
    unsigned u = __builtin_bit_cast(unsigned, f);
    return (bfu)((u + 0x7fffu + ((u >> 16) & 1u)) >> 16);
}
__device__ __forceinline__ float bf2f(bfu h) {
    unsigned u = ((unsigned)h) << 16;
    return __builtin_bit_cast(float, u);
}

__device__ __forceinline__ void gload_lds16(const bfu* g, bfu* l) {
    __builtin_amdgcn_global_load_lds(
        (const __attribute__((address_space(1))) void*)g,
        (__attribute__((address_space(3))) void*)l, 16, 0, 0);
}

// ---------------------------------------------------------------------------
// KNN — FROZEN r4 version (measured 715-752 us across 5 runs; 0 conflicts,
// no spills). SIX failed improvement attempts:
//   r5  contiguous->interleaved slices: fixed conflicts, neutral time
//   r6  launch_bounds(256) VGPR cap 64/128: spill, 4.6x slower
//   r8  launch_bounds(256,4): spill (VGPR 64), 3.8x slower
//   r11 wave-per-query branchy: 2.3x slower (cold gates, 6 merge levels)
//   r13 branchless insert: 1.6x slower (2x VALU work; gate prunes well)
//   r15 launch_bounds(256,3): compiler over-squeezed to VGPR 84, spill
// Structural constraint: ~160-VGPR working set -> 2 waves/SIMD, latency-bound.
// DO NOT TOUCH. No launch_bounds min-waves arg, full 64KB tile, gated scan.
// ---------------------------------------------------------------------------
#define TPQ 8                    // threads per query
#define QPB 32                   // queries per block (QPB*TPQ = 256)

__device__ __forceinline__ void knn_merge_level(float* bd, int* bi, int lvl)
{
    float pd[KNN]; int pi[KNN];
#pragma unroll
    for (int i = 0; i < KNN; ++i) {              // partner's list, reversed
        pd[i] = __shfl_xor(bd[KNN-1-i], lvl);
        pi[i] = __shfl_xor(bi[KNN-1-i], lvl);
    }
#pragma unroll
    for (int i = 0; i < KNN; ++i) {              // lex-min -> lowest 16, bitonic
        bool take = (pd[i] < bd[i]) || (pd[i] == bd[i] && pi[i] < bi[i]);
        if (take) { bd[i] = pd[i]; bi[i] = pi[i]; }
    }
#pragma unroll
    for (int s = 8; s >= 1; s >>= 1) {           // bitonic merge network
#pragma unroll
        for (int i = 0; i < KNN; ++i) {
            if ((i & s) == 0) {
                const int j = i + s;
                bool sw = (bd[j] < bd[i]) || (bd[j] == bd[i] && bi[j] < bi[i]);
                if (sw) {
                    float td = bd[i]; bd[i] = bd[j]; bd[j] = td;
                    int   ti = bi[i]; bi[i] = bi[j]; bi[j] = ti;
                }
            }
        }
    }
}

__global__ __launch_bounds__(256) void knn_kernel(const float* __restrict__ xyz,
                                                  int* __restrict__ knn_out)
{
    __shared__ float4 pts[NPTS];   // 64 KB
    const int b    = blockIdx.y;
    const int tid  = threadIdx.x;
    const int qloc = tid >> 3;            // 0..31
    const int sub  = tid & 7;             // 0..7
    const int n    = blockIdx.x * QPB + qloc;

    const float* bx = xyz + (size_t)b * NPTS * 3;
    for (int i = tid; i < NPTS; i += 256) {
        float x = bx[i*3+0], y = bx[i*3+1], z = bx[i*3+2];
        pts[i] = make_float4(x, y, z, x*x + y*y + z*z);
    }
    __syncthreads();

    const float4 me = pts[n];
    float bd[KNN];
    int   bi[KNN];
#pragma unroll
    for (int i = 0; i < KNN; ++i) { bd[i] = 3.4e38f; bi[i] = -1; }

    // interleaved slice: m = sub + 8*t, t in [0, 512)
    for (int t0 = 0; t0 < NPTS / TPQ; t0 += 8) {
        float d[8];
#pragma unroll
        for (int j = 0; j < 8; ++j) {
            float4 o = pts[sub + ((t0 + j) << 3)];
            d[j] = me.w + o.w - 2.f*(me.x*o.x + me.y*o.y + me.z*o.z);
        }
        float mn = fminf(fminf(fminf(d[0],d[1]),fminf(d[2],d[3])),
                         fminf(fminf(d[4],d[5]),fminf(d[6],d[7])));
        if (mn < bd[KNN-1]) {
#pragma unroll
            for (int j = 0; j < 8; ++j) {
                float dj = d[j];
                if (dj < bd[KNN-1]) {
                    const int m = sub + ((t0 + j) << 3);
#pragma unroll
                    for (int i = KNN-1; i >= 1; --i) {
                        float dp = bd[i-1];
                        if (dp > dj)        { bd[i] = dp; bi[i] = bi[i-1]; }
                        else if (bd[i] > dj){ bd[i] = dj; bi[i] = m; }
                    }
                    if (bd[0] > dj) { bd[0] = dj; bi[0] = m; }
                }
            }
        }
    }

    // merge the 8 per-slice sorted lists (lanes sub^1, sub^2, sub^4)
    knn_merge_level(bd, bi, 1);
    knn_merge_level(bd, bi, 2);
    knn_merge_level(bd, bi, 4);

    // all 8 threads now hold the final sorted list; each writes 2 entries
    int* orow = knn_out + ((size_t)b*NPTS + n) * KNN;
    const int base = b * NPTS;
    orow[sub*2+0] = base + bi[sub*2+0];
    orow[sub*2+1] = base + bi[sub*2+1];
}

// ---------------------------------------------------------------------------
// One-shot weight prep: transpose-convert all 8 weight matrices (one launch).
// ---------------------------------------------------------------------------
__global__ __launch_bounds__(256) void prep_weights(
    const float* __restrict__ fc1_w, const float* __restrict__ wq,
    const float* __restrict__ wk,    const float* __restrict__ wv,
    const float* __restrict__ d2_w,  const float* __restrict__ g1_w,
    const float* __restrict__ g2_w,  const float* __restrict__ fc2_w,
    bfu* __restrict__ fc1T, bfu* __restrict__ qkvT, bfu* __restrict__ d2T,
    bfu* __restrict__ g1T,  bfu* __restrict__ g2T,  bfu* __restrict__ fc2T)
{
    int i = blockIdx.x * 256 + threadIdx.x;
    const int S1 = DPOINT * DMODEL;      // 65536
    const int S2 = DMODEL * DMODEL;      // 262144
    if (i < S1) { fc1T[i] = f2bf(fc1_w[(size_t)(i & 127) * DMODEL + (i >> 7)]); return; }
    i -= S1;
    if (i < S2) { qkvT[i]        = f2bf(wq[(size_t)(i & 511) * DMODEL + (i >> 9)]); return; }
    i -= S2;
    if (i < S2) { qkvT[S2 + i]   = f2bf(wk[(size_t)(i & 511) * DMODEL + (i >> 9)]); return; }
    i -= S2;
    if (i < S2) { qkvT[2*S2 + i] = f2bf(wv[(size_t)(i & 511) * DMODEL + (i >> 9)]); return; }
    i -= S2;
    if (i < S2) { d2T[i] = f2bf(d2_w[(size_t)(i & 511) * DMODEL + (i >> 9)]); return; }
    i -= S2;
    if (i < S2) { g1T[i] = f2bf(g1_w[(size_t)(i & 511) * DMODEL + (i >> 9)]); return; }
    i -= S2;
    if (i < S2) { g2T[i] = f2bf(g2_w[(size_t)(i & 511) * DMODEL + (i >> 9)]); return; }
    i -= S2;
    if (i < S1) { fc2T[i] = f2bf(fc2_w[(size_t)(i & 511) * DPOINT + (i >> 9)]); return; }
}

__global__ __launch_bounds__(256) void cvt_bf16(const float* __restrict__ src,
                                                bfu* __restrict__ dst, int n4)
{
    int i = blockIdx.x * 256 + threadIdx.x;
    if (i < n4) {
        float4 v = ((const float4*)src)[i];
        bfu* d = dst + (size_t)i * 4;
        d[0] = f2bf(v.x); d[1] = f2bf(v.y); d[2] = f2bf(v.z); d[3] = f2bf(v.w);
    }
}

// ---------------------------------------------------------------------------
// pos_h = relu(rel @ d1_w + d1_b), materialized per chunk (memory-bound).
// ---------------------------------------------------------------------------
__global__ __launch_bounds__(256) void pos_h_kernel(
    const float* __restrict__ xyz, const int* __restrict__ knng,
    const float* __restrict__ d1w, const float* __restrict__ d1b,
    bfu* __restrict__ out, int row_base)
{
    const int idx  = blockIdx.x * 256 + threadIdx.x;
    const int rloc = idx >> 6;                // chunk-local row
    const int c0   = (idx & 63) * 8;
    const int grow = row_base + rloc;
    const int p    = grow >> 4;
    const int nb   = knng[grow];
    const float rx = xyz[(size_t)p*3+0] - xyz[(size_t)nb*3+0];
    const float ry = xyz[(size_t)p*3+1] - xyz[(size_t)nb*3+1];
    const float rz = xyz[(size_t)p*3+2] - xyz[(size_t)nb*3+2];
    short8 ov;
#pragma unroll
    for (int j = 0; j < 8; ++j) {
        const int k = c0 + j;
        float v = d1b[k];
        v = fmaf(rx, d1w[k],        v);
        v = fmaf(ry, d1w[512 + k],  v);
        v = fmaf(rz, d1w[1024 + k], v);
        ov[j] = (short)f2bf(fmaxf(v, 0.f));
    }
    *(short8*)&out[(size_t)rloc * DMODEL + c0] = ov;
}

// ---------------------------------------------------------------------------
// MFMA GEMM, m97 structure, BMt x 128 tile, BK=64, 4 waves, 16x16x32 bf16,
// global_load_lds width 16, 2 barriers per K-step. Plain bf16 A (gload_lds).
// 1D grid + bijective XCD-chunk swizzle + bn-fastest (r10: -200us wall).
// AIN:  epilogue writes posc (Cout, bf16) AND ainb = q[p]-k[g]+pos (auxb).
// SMAX: fused scale+softmax(16 neighbor rows)+attn write(f32)+res reduce.
// ---------------------------------------------------------------------------
template<int BMt, bool BIAS, bool RELU, bool OUTBF, bool RESID, bool AIN, bool SMAX>
__global__ __launch_bounds__(256) void gemm_mfma(
    const bfu* __restrict__ A, const bfu* __restrict__ BT,
    const float* __restrict__ bias, const float* __restrict__ resid,
    void* __restrict__ Cout, int M, int Kd, int Nd,
    const int* __restrict__ knng,
    const bfu* __restrict__ qb, const bfu* __restrict__ kb,
    const bfu* __restrict__ posc, const bfu* __restrict__ vb,
    bfu* __restrict__ auxb, int row_base)
{
    constexpr int MF  = BMt / 32;     // m-fragments per wave (4 or 2)
    constexpr int RPW = BMt / 4;      // A rows staged per wave

    __shared__ bfu As[BMt * BK];
    __shared__ bfu Bs[BN * BK];

    const int tid  = threadIdx.x;
    const int lane = tid & 63;
    const int w    = tid >> 6;

    // XCD-chunk swizzle (bijective since gridDim.x % 8 == 0), bn fastest
    const int nbn     = Nd / BN;
    const int q8      = gridDim.x >> 3;
    const int logical = (blockIdx.x & 7) * q8 + (blockIdx.x >> 3);
    const int bm      = (logical / nbn) * BMt;
    const int bn      = (logical % nbn) * BN;

    const int wm   = (w >> 1) * (BMt / 2);
    const int wn   = (w & 1) * 64;
    const int lrow = lane & 15;
    const int kgrp = lane >> 4;

    f32x4 acc[MF][4];
#pragma unroll
    for (int m = 0; m < MF; ++m)
#pragma unroll
        for (int n = 0; n < 4; ++n) acc[m][n] = (f32x4){0.f, 0.f, 0.f, 0.f};

    for (int k0 = 0; k0 < Kd; k0 += BK) {
        __syncthreads();   // previous tile fully consumed

        // ---- stage B
        {
            int r0 = w * 32;
            const bfu* gB = BT + (size_t)(bn + r0 + (lane >> 3)) * Kd + k0 + (lane & 7) * 8;
            bfu* lB = Bs + r0 * BK;
#pragma unroll
            for (int i = 0; i < 4; ++i)
                gload_lds16(gB + (size_t)i * 8 * Kd, lB + i * 8 * BK);
        }
        // ---- stage A
        {
            int r0 = w * RPW;
            const bfu* gA = A + (size_t)(bm + r0 + (lane >> 3)) * Kd + k0 + (lane & 7) * 8;
            bfu* lA = As + r0 * BK;
#pragma unroll
            for (int i = 0; i < RPW / 8; ++i)
                gload_lds16(gA + (size_t)i * 8 * Kd, lA + i * 8 * BK);
        }

        __syncthreads();

        // ---- compute
#pragma unroll
        for (int kk = 0; kk < BK; kk += 32) {
            short8 af[MF], bfr[4];
#pragma unroll
            for (int m = 0; m < MF; ++m)
                af[m] = *(const short8*)&As[(wm + m * 16 + lrow) * BK + kk + kgrp * 8];
#pragma unroll
            for (int n = 0; n < 4; ++n)
                bfr[n] = *(const short8*)&Bs[(wn + n * 16 + lrow) * BK + kk + kgrp * 8];
#pragma unroll
            for (int m = 0; m < MF; ++m)
#pragma unroll
                for (int n = 0; n < 4; ++n)
                    acc[m][n] = __builtin_amdgcn_mfma_f32_16x16x32_bf16(
                        af[m], bfr[n], acc[m][n], 0, 0, 0);
        }
    }

    if constexpr (AIN) {
        // pos = acc + bias -> posc (bf16, Cout); ainb = q[p]-k[g]+pos (auxb)
#pragma unroll
        for (int m = 0; m < MF; ++m) {
            const int row0 = bm + wm + m * 16 + kgrp * 4;    // chunk-local
            int p4[4], g4[4];
#pragma unroll
            for (int r = 0; r < 4; ++r) {
                const int grow = row_base + row0 + r;
                p4[r] = grow >> 4;
                g4[r] = knng[grow];
            }
#pragma unroll
            for (int n = 0; n < 4; ++n) {
                const int col = bn + wn + n * 16 + lrow;
                const float bv = bias[col];
#pragma unroll
                for (int r = 0; r < 4; ++r) {
                    const size_t o = (size_t)(row0 + r) * DMODEL + col;
                    bfu pb = f2bf(acc[m][n][r] + bv);
                    ((bfu*)Cout)[o] = pb;
                    float qv = bf2f(qb[(size_t)p4[r] * QKVLD + col]);
                    float kv = bf2f(kb[(size_t)g4[r] * QKVLD + col]);
                    auxb[o] = f2bf(qv - kv + bf2f(pb));
                }
            }
        }
        return;
    }

    if constexpr (SMAX) {
        // logits -> softmax over the 16 neighbor rows of each point -> attn
        // (f32, to Cout) + res partial reduce (bf16, to auxb).
        const float scale = 0.044194173824159216f;   // 1/sqrt(512)
#pragma unroll
        for (int m = 0; m < MF; ++m) {
            const int row0 = bm + wm + m * 16 + kgrp * 4;    // chunk-local
            const int ploc = (bm + wm + m * 16) >> 4;        // chunk-local point
            int gnb4[4];
#pragma unroll
            for (int r = 0; r < 4; ++r) gnb4[r] = knng[(size_t)row_base + row0 + r];
#pragma unroll
            for (int n = 0; n < 4; ++n) {
                const int col = bn + wn + n * 16 + lrow;
                const float bv = bias[col];
                float v0 = (acc[m][n][0] + bv) * scale;
                float v1 = (acc[m][n][1] + bv) * scale;
                float v2 = (acc[m][n][2] + bv) * scale;
                float v3 = (acc[m][n][3] + bv) * scale;
                float mx = fmaxf(fmaxf(v0, v1), fmaxf(v2, v3));
                mx = fmaxf(mx, __shfl_xor(mx, 16));
                mx = fmaxf(mx, __shfl_xor(mx, 32));
                float e0 = __expf(v0 - mx), e1 = __expf(v1 - mx);
                float e2 = __expf(v2 - mx), e3 = __expf(v3 - mx);
                float s = e0 + e1 + e2 + e3;
                s += __shfl_xor(s, 16);
                s += __shfl_xor(s, 32);
                const float inv = 1.f / s;
                float a0 = e0*inv, a1 = e1*inv, a2 = e2*inv, a3 = e3*inv;
                float* ao = (float*)Cout;
                ao[(size_t)(row0 + 0) * DMODEL + col] = a0;
                ao[(size_t)(row0 + 1) * DMODEL + col] = a1;
                ao[(size_t)(row0 + 2) * DMODEL + col] = a2;
                ao[(size_t)(row0 + 3) * DMODEL + col] = a3;
                float res = 0.f;
                res = fmaf(a0, bf2f(vb[(size_t)gnb4[0]*QKVLD + col]) + bf2f(posc[(size_t)(row0+0)*DMODEL + col]), res);
                res = fmaf(a1, bf2f(vb[(size_t)gnb4[1]*QKVLD + col]) + bf2f(posc[(size_t)(row0+1)*DMODEL + col]), res);
                res = fmaf(a2, bf2f(vb[(size_t)gnb4[2]*QKVLD + col]) + bf2f(posc[(size_t)(row0+2)*DMODEL + col]), res);
                res = fmaf(a3, bf2f(vb[(size_t)gnb4[3]*QKVLD + col]) + bf2f(posc[(size_t)(row0+3)*DMODEL + col]), res);
                res += __shfl_xor(res, 16);
                res += __shfl_xor(res, 32);
                if (kgrp == 0) {
                    const size_t pglob = (size_t)(row_base >> 4) + ploc;
                    auxb[pglob * DMODEL + col] = f2bf(res);
                }
            }
        }
        return;
    }

    // ---- standard epilogue: C row = (lane>>4)*4 + reg, col = lane&15
#pragma unroll
    for (int m = 0; m < MF; ++m) {
#pragma unroll
        for (int n = 0; n < 4; ++n) {
            int col = bn + wn + n * 16 + lrow;
            float bv = BIAS ? bias[col] : 0.f;
#pragma unroll
            for (int r = 0; r < 4; ++r) {
                int row = bm + wm + m * 16 + kgrp * 4 + r;
                float v = acc[m][n][r] + bv;
                if (RESID) v += resid[(size_t)row * Nd + col];
                if (RELU)  v = fmaxf(v, 0.f);
                if (OUTBF) ((bfu*)Cout)[(size_t)row * Nd + col] = f2bf(v);
                else     ((float*)Cout)[(size_t)row * Nd + col] = v;
            }
        }
    }
}

// ---------------------------------------------------------------------------
extern "C" void kernel_launch(void* const* d_in, const int* in_sizes, int n_in,
                              void* d_out, int out_size, void* d_ws, size_t ws_size,
                              hipStream_t stream)
{
    const float* xyz      = (const float*)d_in[0];
    const float* features = (const float*)d_in[1];
    const float* fc1_w    = (const float*)d_in[2];
    const float* fc1_b    = (const float*)d_in[3];
    const float* fc2_w    = (const float*)d_in[4];
    const float* fc2_b    = (const float*)d_in[5];
    const float* wq       = (const float*)d_in[6];
    const float* wk       = (const float*)d_in[7];
    const float* wv       = (const float*)d_in[8];
    const float* d1_w     = (const float*)d_in[9];
    const float* d1_b     = (const float*)d_in[10];
    const float* d2_w     = (const float*)d_in[11];
    const float* d2_b     = (const float*)d_in[12];
    const float* g1_w     = (const float*)d_in[13];
    const float* g1_b     = (const float*)d_in[14];
    const float* g2_w     = (const float*)d_in[15];
    const float* g2_b     = (const float*)d_in[16];

    const size_t Mpts  = (size_t)NBATCH * NPTS;      // 16384
    const size_t Mrows = Mpts * KNN;                 // 262144
    float* out_res  = (float*)d_out;                 // [16384,128]
    float* out_attn = (float*)d_out + Mpts * DPOINT; // [16384,16,512] f32

    // ---- workspace layout (resb aliases xb: xb dead after qkv GEMM)
    size_t off = 0;
    auto ab = [&](size_t elems) { bfu* r = (bfu*)((char*)d_ws + off); off += elems * 2; return r; };
    bfu* fc1T  = ab((size_t)DMODEL * DPOINT);        // [512][128]
    bfu* qkvT  = ab((size_t)QKVLD * DMODEL);         // [1536][512] = wq^T|wk^T|wv^T
    bfu* d2T   = ab((size_t)DMODEL * DMODEL);
    bfu* g1T   = ab((size_t)DMODEL * DMODEL);
    bfu* g2T   = ab((size_t)DMODEL * DMODEL);
    bfu* fc2T  = ab((size_t)DPOINT * DMODEL);        // [128][512]
    bfu* featb = ab(Mpts * DPOINT);
    bfu* xb    = ab(Mpts * DMODEL);                  // reused as resb
    bfu* qkvb  = ab(Mpts * QKVLD);                   // [16384][1536] q|k|v
    bfu* resb  = xb;
    int* knng  = (int*)((char*)d_ws + off); off += Mrows * 4;

    // prefer nchunk=4: 3 x 64MB chunk buffers -> L3-resident, grid still full
    int nchunk = 32;
    {
        const int cands[4] = {4, 8, 16, 32};
        for (int i = 0; i < 4; ++i) {
            size_t need = off + 3ull * (Mrows / cands[i]) * DMODEL * 2;
            if (need <= ws_size) { nchunk = cands[i]; break; }
        }
    }
    const size_t Rc  = Mrows / nchunk;               // rows per chunk
    bfu* posc = ab(Rc * DMODEL);
    bfu* hc   = ab(Rc * DMODEL);
    bfu* ainb = ab(Rc * DMODEL);

    // ---- KNN + conversions
    knn_kernel<<<dim3(NPTS/QPB, NBATCH), 256, 0, stream>>>(xyz, knng);

    {
        const int total = 2 * DPOINT * DMODEL + 6 * DMODEL * DMODEL;
        prep_weights<<<dim3((total + 255) / 256), 256, 0, stream>>>(
            fc1_w, wq, wk, wv, d2_w, g1_w, g2_w, fc2_w,
            fc1T, qkvT, d2T, g1T, g2T, fc2T);
    }
    cvt_bf16<<<dim3((Mpts*DPOINT/4+255)/256), 256, 0, stream>>>(features, featb, (int)(Mpts*DPOINT/4));

#define GARGS(Ap, Bp, biasp, residp, Cp, M_, K_, N_, auxp, rb) \
    (Ap), (Bp), (biasp), (residp), (Cp), (int)(M_), (int)(K_), (int)(N_), \
    knng, qkvb, qkvb + DMODEL, posc, qkvb + 2*DMODEL, (auxp), (int)(rb)

    // ---- stage B: x = feat @ fc1 + b ; qkv = x @ [wq|wk|wv]  (one GEMM)
    gemm_mfma<128, true,  false, true,  false, false, false><<<dim3((Mpts/128)*(DMODEL/BN)), 256, 0, stream>>>(
        GARGS(featb, fc1T, fc1_b, nullptr, xb, Mpts, DPOINT, DMODEL, resb, 0));
    gemm_mfma<128, false, false, true,  false, false, false><<<dim3((Mpts/128)*(QKVLD/BN)), 256, 0, stream>>>(
        GARGS(xb, qkvT, nullptr, nullptr, qkvb, Mpts, DMODEL, QKVLD, resb, 0));

    // ---- chunked per-neighbor pipeline (all GEMMs plain, gload_lds-staged)
    for (int c = 0; c < nchunk; ++c) {
        const size_t rb = (size_t)c * Rc;
        float* attn_c = out_attn + rb * DMODEL;

        // pos_h = relu(rel@d1+b1) materialized into hc (memory-bound)
        pos_h_kernel<<<dim3((unsigned)(Rc/4)), 256, 0, stream>>>(xyz, knng, d1_w, d1_b, hc, (int)rb);

#define CHUNK_LAUNCH(BMT) \
        gemm_mfma<BMT, true, false, true, false, true, false><<<dim3((unsigned)((Rc/BMT)*(DMODEL/BN))), 256, 0, stream>>>( \
            GARGS(hc, d2T, d2_b, nullptr, posc, Rc, DMODEL, DMODEL, ainb, rb)); \
        gemm_mfma<BMT, true, true,  true, false, false, false><<<dim3((unsigned)((Rc/BMT)*(DMODEL/BN))), 256, 0, stream>>>( \
            GARGS(ainb, g1T, g1_b, nullptr, hc, Rc, DMODEL, DMODEL, resb, rb)); \
        gemm_mfma<BMT, false, false, false, false, false, true><<<dim3((unsigned)((Rc/BMT)*(DMODEL/BN))), 256, 0, stream>>>( \
            GARGS(hc, g2T, g2_b, nullptr, attn_c, Rc, DMODEL, DMODEL, resb, rb));

        if (Rc >= 32768) { CHUNK_LAUNCH(128) }
        else             { CHUNK_LAUNCH(64)  }
#undef CHUNK_LAUNCH
    }

    // ---- out = res @ fc2 + b + features
    gemm_mfma<128, true, false, false, true, false, false><<<dim3((Mpts/128)*(DPOINT/BN)), 256, 0, stream>>>(
        GARGS(resb, fc2T, fc2_b, features, out_res, Mpts, DMODEL, DPOINT, resb, 0));
#undef GARGS
}